// Round 20
// baseline (609.640 us; speedup 1.0000x reference)
//
#include <hip/hip_runtime.h>

typedef __bf16 bf16;
typedef bf16 bf16x4 __attribute__((ext_vector_type(4)));
typedef bf16 bf16x8 __attribute__((ext_vector_type(8)));
typedef float f32x4 __attribute__((ext_vector_type(4)));

// ws layout (bf16 element offsets):
//   PK1  [4][4][4][64][8] = 32768    GEMM1 weights, fragment-packed
//   PK2  [4][8][4][64][8] = 65536    W1
//   PK3  [4][8][4][64][8] = 65536    W2
//   QG   bf16[64][256]    = 16384    gate (split path)
//   QGF  float[64][256]   (= 32768 bf16 slots)  gate (fused path)
//   AKH  bf16[E][256]     = 204.8 MB  AK, overwritten in-place by H (split)
#define WS_PK1    0
#define WS_PK2    32768
#define WS_PK3    98304
#define WS_QG     163840
#define WS_QGF_B  180224
#define WS_AKH    212992
#define WS_SPLIT_BYTES (425984ull + 204800000ull)

// ---------- prep: pack weights into per-(cg,kk,ai) contiguous 1KB fragments ----------
__global__ void prep_weights(const float* __restrict__ Wrel,
                             const float* __restrict__ Wnode,
                             const float* __restrict__ W1,
                             const float* __restrict__ W2,
                             bf16* __restrict__ ws) {
  int id = blockIdx.x * 256 + threadIdx.x;
  if (id < 32768) {                       // PK1: cg(4) kk(4) ai(4) l(64) j(8)
    int cg = id >> 13, rem = id & 8191;
    int kk = rem >> 11;
    int ai = (rem >> 9) & 3;
    int l  = (rem >> 3) & 63;
    int j  = rem & 7;
    int n  = (cg & 1) * 64 + ai * 16 + (l & 15);
    int k  = kk * 32 + (l >> 4) * 8 + j;
    const float* src = (cg >> 1) ? Wnode : Wrel;
    ws[WS_PK1 + id] = (bf16)src[k * 128 + n];
  } else if (id < 98304) {                // PK2: cg(4) kk(8) ai(4) l(64) j(8)
    int t = id - 32768;
    int cg = t >> 14, rem = t & 16383;
    int kk = rem >> 11;
    int ai = (rem >> 9) & 3;
    int l  = (rem >> 3) & 63;
    int j  = rem & 7;
    int n  = cg * 64 + ai * 16 + (l & 15);
    int k  = kk * 32 + (l >> 4) * 8 + j;
    ws[WS_PK2 + t] = (bf16)W1[k * 256 + n];
  } else if (id < 163840) {               // PK3
    int t = id - 98304;
    int cg = t >> 14, rem = t & 16383;
    int kk = rem >> 11;
    int ai = (rem >> 9) & 3;
    int l  = (rem >> 3) & 63;
    int j  = rem & 7;
    int n  = cg * 64 + ai * 16 + (l & 15);
    int k  = kk * 32 + (l >> 4) * 8 + j;
    ws[WS_PK3 + t] = (bf16)W2[k * 256 + n];
  }
}

// ---------- prep: gate tables, fp32 (fused) + bf16 (split) ----------
__global__ void prep_qg(const float* __restrict__ question,
                        const float* __restrict__ Wq,
                        float* __restrict__ qgf,
                        bf16* __restrict__ qg) {
  int b = blockIdx.x, c = threadIdx.x;
  float s = 0.f;
#pragma unroll 8
  for (int k = 0; k < 128; ++k) s += question[b * 128 + k] * Wq[k * 256 + c];
  float v = 1.f / (1.f + expf(-s));
  qgf[b * 256 + c] = v;
  qg[b * 256 + c]  = (bf16)v;
}

// tanh-form GELU, exp2-direct. max |diff vs erf-GELU| ~5e-4 << 1.23e-2 budget.
__device__ __forceinline__ float gelu_fast(float x) {
  float m = x * x;
  float t = fmaf(0.10294537f, m, 2.30220790f);
  float e = __builtin_amdgcn_exp2f(t * x);
  float r = __builtin_amdgcn_rcpf(e + 1.f);
  return x - x * r;
}

typedef __attribute__((address_space(1))) const void gq_t;
typedef __attribute__((address_space(3))) void lq_t;
#define GLD16(g, s) __builtin_amdgcn_global_load_lds((gq_t*)(g), (lq_t*)(s), 16, 0, 0)
#define SB() __builtin_amdgcn_sched_barrier(0xF)
#define WAIT_VM4()   { asm volatile("s_waitcnt vmcnt(4)" ::: "memory"); SB(); }
#define WAIT_VM0()   { asm volatile("s_waitcnt vmcnt(0)" ::: "memory"); SB(); }
#define WAIT_LGKM0() { asm volatile("s_waitcnt lgkmcnt(0)" ::: "memory"); SB(); }
#define BAR() __builtin_amdgcn_s_barrier()

// ================= SPLIT PATH =================
// K1: AK[e][256] = concat(rel@Wrel, node@Wnode)*gate. 64 edges/block, 4 waves.
__global__ __launch_bounds__(256, 3) void k1_ak(
    const float* __restrict__ rel_tok,
    const float* __restrict__ node_tok,
    const int*   __restrict__ tail_idx,
    const int*   __restrict__ ebatch,
    const bf16*  __restrict__ pk1,
    const bf16*  __restrict__ qg,
    bf16* __restrict__ akh)
{
  __shared__ char s_tok[32768];   // [2][64][128] bf16 swizzled
  const int tid = threadIdx.x;
  const int cg = tid >> 6, l = tid & 63, lo = l & 15, hi = l >> 4;
  const int base = blockIdx.x * 64;
  const int h1 = cg >> 1;

  int ebv[4];
#pragma unroll
  for (int bj = 0; bj < 4; ++bj) ebv[bj] = ebatch[base + bj * 16 + lo];
  bf16x4 gv[4][4];
#pragma unroll
  for (int bj = 0; bj < 4; ++bj)
#pragma unroll
    for (int ai = 0; ai < 4; ++ai)
      gv[bj][ai] = *(const bf16x4*)(qg + ebv[bj] * 256 + cg * 64 + ai * 16 + hi * 4);

  {
    const float4* g = (const float4*)rel_tok + (size_t)base * 32;
#pragma unroll
    for (int i = 0; i < 8; ++i) {
      int idx = tid + i * 256;
      int row = idx >> 5, c4 = idx & 31;
      float4 v = g[idx];
      bf16x4 b; b[0] = (bf16)v.x; b[1] = (bf16)v.y; b[2] = (bf16)v.z; b[3] = (bf16)v.w;
      int off = row * 256 + ((c4 * 8) ^ ((row & 15) << 4));
      *(bf16x4*)(s_tok + off) = b;
    }
#pragma unroll
    for (int i = 0; i < 8; ++i) {
      int idx = tid + i * 256;
      int row = idx >> 5, c4 = idx & 31;
      int tail = tail_idx[base + row];
      float4 v = ((const float4*)node_tok)[(size_t)tail * 32 + c4];
      bf16x4 b; b[0] = (bf16)v.x; b[1] = (bf16)v.y; b[2] = (bf16)v.z; b[3] = (bf16)v.w;
      int off = 16384 + row * 256 + ((c4 * 8) ^ ((row & 15) << 4));
      *(bf16x4*)(s_tok + off) = b;
    }
  }
  __syncthreads();

  const f32x4 zero4 = {0.f, 0.f, 0.f, 0.f};
  f32x4 acc[4][4];
#pragma unroll
  for (int ai = 0; ai < 4; ++ai)
#pragma unroll
    for (int bj = 0; bj < 4; ++bj) acc[ai][bj] = zero4;

#pragma unroll
  for (int kk = 0; kk < 4; ++kk) {
    bf16x8 a[4];
#pragma unroll
    for (int ai = 0; ai < 4; ++ai)
      a[ai] = *(const bf16x8*)(pk1 + cg * 8192 + (kk * 4 + ai) * 512 + l * 8);
#pragma unroll
    for (int bj = 0; bj < 4; ++bj) {
      int e = bj * 16 + lo;
      bf16x8 b = *(const bf16x8*)(s_tok + h1 * 16384 + e * 256 +
                                  ((kk * 64 + hi * 16) ^ ((e & 15) << 4)));
#pragma unroll
      for (int ai = 0; ai < 4; ++ai)
        acc[ai][bj] = __builtin_amdgcn_mfma_f32_16x16x32_bf16(a[ai], b, acc[ai][bj], 0, 0, 0);
    }
  }

#pragma unroll
  for (int bj = 0; bj < 4; ++bj) {
    int e = bj * 16 + lo;
#pragma unroll
    for (int ai = 0; ai < 4; ++ai) {
      int col0 = cg * 64 + ai * 16 + hi * 4;
      bf16x4 pk;
      pk[0] = (bf16)(acc[ai][bj][0] * (float)gv[bj][ai][0]);
      pk[1] = (bf16)(acc[ai][bj][1] * (float)gv[bj][ai][1]);
      pk[2] = (bf16)(acc[ai][bj][2] * (float)gv[bj][ai][2]);
      pk[3] = (bf16)(acc[ai][bj][3] * (float)gv[bj][ai][3]);
      *(bf16x4*)(akh + (size_t)(base + e) * 256 + col0) = pk;
    }
  }
}

// K2: in-place AK -> H = gelu(AK@W1 + b1). B-frags direct from global (L3-hot).
__global__ __launch_bounds__(256, 3) void k2_mlp1(
    bf16* __restrict__ akh,
    const bf16* __restrict__ pk2,
    const float* __restrict__ b1)
{
  const int tid = threadIdx.x;
  const int cg = tid >> 6, l = tid & 63, lo = l & 15, hi = l >> 4;
  const int base = blockIdx.x * 64;

  float4 b1v[4];
#pragma unroll
  for (int ai = 0; ai < 4; ++ai)
    b1v[ai] = *(const float4*)(b1 + cg * 64 + ai * 16 + hi * 4);

  const f32x4 zero4 = {0.f, 0.f, 0.f, 0.f};
  f32x4 acc[4][4];
#pragma unroll
  for (int ai = 0; ai < 4; ++ai)
#pragma unroll
    for (int bj = 0; bj < 4; ++bj) acc[ai][bj] = zero4;

#pragma unroll
  for (int kk = 0; kk < 8; ++kk) {
    bf16x8 a[4];
#pragma unroll
    for (int ai = 0; ai < 4; ++ai)
      a[ai] = *(const bf16x8*)(pk2 + cg * 16384 + (kk * 4 + ai) * 512 + l * 8);
#pragma unroll
    for (int bj = 0; bj < 4; ++bj) {
      int e = bj * 16 + lo;
      bf16x8 b = *(const bf16x8*)(akh + (size_t)(base + e) * 256 + kk * 32 + hi * 8);
#pragma unroll
      for (int ai = 0; ai < 4; ++ai)
        acc[ai][bj] = __builtin_amdgcn_mfma_f32_16x16x32_bf16(a[ai], b, acc[ai][bj], 0, 0, 0);
    }
  }
  // all AK reads complete before any in-place H write (vmcnt drain + barrier)
  asm volatile("s_waitcnt vmcnt(0)" ::: "memory");
  __syncthreads();

#pragma unroll
  for (int bj = 0; bj < 4; ++bj) {
    int e = bj * 16 + lo;
#pragma unroll
    for (int ai = 0; ai < 4; ++ai) {
      int col0 = cg * 64 + ai * 16 + hi * 4;
      bf16x4 pk;
      pk[0] = (bf16)gelu_fast(acc[ai][bj][0] + b1v[ai].x);
      pk[1] = (bf16)gelu_fast(acc[ai][bj][1] + b1v[ai].y);
      pk[2] = (bf16)gelu_fast(acc[ai][bj][2] + b1v[ai].z);
      pk[3] = (bf16)gelu_fast(acc[ai][bj][3] + b1v[ai].w);
      *(bf16x4*)(akh + (size_t)(base + e) * 256 + col0) = pk;
    }
  }
}

// K3: out = H@W2 + b2 (fp32). Barrier-free.
__global__ __launch_bounds__(256, 3) void k3_mlp2(
    const bf16* __restrict__ akh,
    const bf16* __restrict__ pk3,
    const float* __restrict__ b2,
    float* __restrict__ out)
{
  const int tid = threadIdx.x;
  const int cg = tid >> 6, l = tid & 63, lo = l & 15, hi = l >> 4;
  const int base = blockIdx.x * 64;

  float4 b2v[4];
#pragma unroll
  for (int ai = 0; ai < 4; ++ai)
    b2v[ai] = *(const float4*)(b2 + cg * 64 + ai * 16 + hi * 4);

  const f32x4 zero4 = {0.f, 0.f, 0.f, 0.f};
  f32x4 acc[4][4];
#pragma unroll
  for (int ai = 0; ai < 4; ++ai)
#pragma unroll
    for (int bj = 0; bj < 4; ++bj) acc[ai][bj] = zero4;

#pragma unroll
  for (int kk = 0; kk < 8; ++kk) {
    bf16x8 a[4];
#pragma unroll
    for (int ai = 0; ai < 4; ++ai)
      a[ai] = *(const bf16x8*)(pk3 + cg * 16384 + (kk * 4 + ai) * 512 + l * 8);
#pragma unroll
    for (int bj = 0; bj < 4; ++bj) {
      int e = bj * 16 + lo;
      bf16x8 b = *(const bf16x8*)(akh + (size_t)(base + e) * 256 + kk * 32 + hi * 8);
#pragma unroll
      for (int ai = 0; ai < 4; ++ai)
        acc[ai][bj] = __builtin_amdgcn_mfma_f32_16x16x32_bf16(a[ai], b, acc[ai][bj], 0, 0, 0);
    }
  }

#pragma unroll
  for (int bj = 0; bj < 4; ++bj) {
    int e = bj * 16 + lo;
#pragma unroll
    for (int ai = 0; ai < 4; ++ai) {
      int col0 = cg * 64 + ai * 16 + hi * 4;
      float4 o;
      o.x = acc[ai][bj][0] + b2v[ai].x;
      o.y = acc[ai][bj][1] + b2v[ai].y;
      o.z = acc[ai][bj][2] + b2v[ai].z;
      o.w = acc[ai][bj][3] + b2v[ai].w;
      *(float4*)(out + (size_t)(base + e) * 256 + col0) = o;
    }
  }
}

// ================= FUSED FALLBACK (R19 champion, unchanged) =================
__global__ __launch_bounds__(256, 2) void fused_main(
    const float* __restrict__ rel_tok,
    const float* __restrict__ node_tok,
    const int*   __restrict__ tail_idx,
    const int*   __restrict__ ebatch,
    const bf16*  __restrict__ pk1,
    const bf16*  __restrict__ pk2,
    const bf16*  __restrict__ pk3,
    const float* __restrict__ qgf,
    const float* __restrict__ b1,
    const float* __restrict__ b2,
    float* __restrict__ out)
{
  __shared__ char  s_buf[32768];
  __shared__ char  s_w[32768];
  __shared__ float s_bias[512];

  const int tid = threadIdx.x;
  const int cg  = tid >> 6;
  const int l   = tid & 63;
  const int lo  = l & 15;
  const int hi  = l >> 4;
  const int base = blockIdx.x * 64;
  const int h1  = cg >> 1;

  auto issue_step = [&](int s) {
    const bf16* g;
    if (s < 4)       g = pk1 + cg * 8192  + s * 2048;
    else if (s < 12) g = pk2 + cg * 16384 + (s - 4) * 2048;
    else             g = pk3 + cg * 16384 + (s - 12) * 2048;
    g += l * 8;
    char* d = s_w + (s & 1) * 16384 + cg * 4096;
#pragma unroll
    for (int ai = 0; ai < 4; ++ai) GLD16(g + ai * 512, d + ai * 1024);
  };

  int ebv[4];
#pragma unroll
  for (int bj = 0; bj < 4; ++bj) ebv[bj] = ebatch[base + bj * 16 + lo];
  float4 gv[4][4];
#pragma unroll
  for (int bj = 0; bj < 4; ++bj)
#pragma unroll
    for (int ai = 0; ai < 4; ++ai)
      gv[bj][ai] = *(const float4*)(qgf + ebv[bj] * 256 + cg * 64 + ai * 16 + hi * 4);
  s_bias[tid]       = b1[tid];
  s_bias[256 + tid] = b2[tid];

  {
    const float4* g = (const float4*)rel_tok + (size_t)base * 32;
#pragma unroll
    for (int i = 0; i < 8; ++i) {
      int idx = tid + i * 256;
      int row = idx >> 5, c4 = idx & 31;
      float4 v = g[idx];
      bf16x4 b; b[0] = (bf16)v.x; b[1] = (bf16)v.y; b[2] = (bf16)v.z; b[3] = (bf16)v.w;
      int off = row * 256 + ((c4 * 8) ^ ((row & 15) << 4));
      *(bf16x4*)(s_buf + off) = b;
    }
#pragma unroll
    for (int i = 0; i < 8; ++i) {
      int idx = tid + i * 256;
      int row = idx >> 5, c4 = idx & 31;
      int tail = tail_idx[base + row];
      float4 v = ((const float4*)node_tok)[(size_t)tail * 32 + c4];
      bf16x4 b; b[0] = (bf16)v.x; b[1] = (bf16)v.y; b[2] = (bf16)v.z; b[3] = (bf16)v.w;
      int off = 16384 + row * 256 + ((c4 * 8) ^ ((row & 15) << 4));
      *(bf16x4*)(s_buf + off) = b;
    }
  }

  WAIT_VM0();
  issue_step(0);
  issue_step(1);
  WAIT_LGKM0();
  BAR();

  const f32x4 zero4 = {0.f, 0.f, 0.f, 0.f};
  const int wb = cg * 4096 + l * 16;

  f32x4 acc1[4][4];
#pragma unroll
  for (int ai = 0; ai < 4; ++ai)
#pragma unroll
    for (int bj = 0; bj < 4; ++bj) acc1[ai][bj] = zero4;

#pragma unroll
  for (int kk = 0; kk < 4; ++kk) {
    const int s = kk;
    WAIT_VM4();
    bf16x8 a[4];
#pragma unroll
    for (int ai = 0; ai < 4; ++ai)
      a[ai] = *(const bf16x8*)(s_w + (s & 1) * 16384 + wb + ai * 1024);
    WAIT_LGKM0();
    issue_step(s + 2);
    __builtin_amdgcn_s_setprio(1);
#pragma unroll
    for (int bj = 0; bj < 4; ++bj) {
      int e = bj * 16 + lo;
      bf16x8 b = *(const bf16x8*)(s_buf + h1 * 16384 + e * 256 +
                                  ((kk * 64 + hi * 16) ^ ((e & 15) << 4)));
#pragma unroll
      for (int ai = 0; ai < 4; ++ai)
        acc1[ai][bj] = __builtin_amdgcn_mfma_f32_16x16x32_bf16(a[ai], b, acc1[ai][bj], 0, 0, 0);
    }
    __builtin_amdgcn_s_setprio(0);
  }
  BAR();

#pragma unroll
  for (int bj = 0; bj < 4; ++bj) {
    int e = bj * 16 + lo;
#pragma unroll
    for (int ai = 0; ai < 4; ++ai) {
      int col0 = cg * 64 + ai * 16 + hi * 4;
      bf16x4 pk;
      pk[0] = (bf16)(acc1[ai][bj][0] * gv[bj][ai].x);
      pk[1] = (bf16)(acc1[ai][bj][1] * gv[bj][ai].y);
      pk[2] = (bf16)(acc1[ai][bj][2] * gv[bj][ai].z);
      pk[3] = (bf16)(acc1[ai][bj][3] * gv[bj][ai].w);
      int off = e * 512 + ((2 * col0) ^ ((e & 15) << 4));
      *(bf16x4*)(s_buf + off) = pk;
    }
  }
  WAIT_LGKM0();
  BAR();

  f32x4 acc2[4][4];
#pragma unroll
  for (int ai = 0; ai < 4; ++ai)
#pragma unroll
    for (int bj = 0; bj < 4; ++bj) acc2[ai][bj] = zero4;

#pragma unroll
  for (int kk = 0; kk < 8; ++kk) {
    const int s = 4 + kk;
    WAIT_VM4();
    bf16x8 a[4];
#pragma unroll
    for (int ai = 0; ai < 4; ++ai)
      a[ai] = *(const bf16x8*)(s_w + (s & 1) * 16384 + wb + ai * 1024);
    WAIT_LGKM0();
    issue_step(s + 2);
    __builtin_amdgcn_s_setprio(1);
#pragma unroll
    for (int bj = 0; bj < 4; ++bj) {
      int e = bj * 16 + lo;
      bf16x8 b = *(const bf16x8*)(s_buf + e * 512 +
                                  ((kk * 64 + hi * 16) ^ ((e & 15) << 4)));
#pragma unroll
      for (int ai = 0; ai < 4; ++ai)
        acc2[ai][bj] = __builtin_amdgcn_mfma_f32_16x16x32_bf16(a[ai], b, acc2[ai][bj], 0, 0, 0);
    }
    __builtin_amdgcn_s_setprio(0);
  }
  BAR();

#pragma unroll
  for (int bj = 0; bj < 4; ++bj) {
    int e = bj * 16 + lo;
#pragma unroll
    for (int ai = 0; ai < 4; ++ai) {
      int col0 = cg * 64 + ai * 16 + hi * 4;
      float4 bv = *(const float4*)(s_bias + col0);
      bf16x4 pk;
      pk[0] = (bf16)gelu_fast(acc2[ai][bj][0] + bv.x);
      pk[1] = (bf16)gelu_fast(acc2[ai][bj][1] + bv.y);
      pk[2] = (bf16)gelu_fast(acc2[ai][bj][2] + bv.z);
      pk[3] = (bf16)gelu_fast(acc2[ai][bj][3] + bv.w);
      int off = e * 512 + ((2 * col0) ^ ((e & 15) << 4));
      *(bf16x4*)(s_buf + off) = pk;
    }
  }
  WAIT_LGKM0();
  BAR();

  f32x4 acc3[4][4];
#pragma unroll
  for (int ai = 0; ai < 4; ++ai)
#pragma unroll
    for (int bj = 0; bj < 4; ++bj) acc3[ai][bj] = zero4;

#pragma unroll
  for (int kk = 0; kk < 8; ++kk) {
    const int s = 12 + kk;
    if (s < 19) { WAIT_VM4(); } else { WAIT_VM0(); }
    bf16x8 a[4];
#pragma unroll
    for (int ai = 0; ai < 4; ++ai)
      a[ai] = *(const bf16x8*)(s_w + (s & 1) * 16384 + wb + ai * 1024);
    WAIT_LGKM0();
    if (s + 2 <= 19) issue_step(s + 2);
    __builtin_amdgcn_s_setprio(1);
#pragma unroll
    for (int bj = 0; bj < 4; ++bj) {
      int e = bj * 16 + lo;
      bf16x8 b = *(const bf16x8*)(s_buf + e * 512 +
                                  ((kk * 64 + hi * 16) ^ ((e & 15) << 4)));
#pragma unroll
      for (int ai = 0; ai < 4; ++ai)
        acc3[ai][bj] = __builtin_amdgcn_mfma_f32_16x16x32_bf16(a[ai], b, acc3[ai][bj], 0, 0, 0);
    }
    __builtin_amdgcn_s_setprio(0);
  }

#pragma unroll
  for (int bj = 0; bj < 4; ++bj) {
    int e = bj * 16 + lo;
#pragma unroll
    for (int ai = 0; ai < 4; ++ai) {
      int col0 = cg * 64 + ai * 16 + hi * 4;
      float4 bv = *(const float4*)(s_bias + 256 + col0);
      float4 o;
      o.x = acc3[ai][bj][0] + bv.x;
      o.y = acc3[ai][bj][1] + bv.y;
      o.z = acc3[ai][bj][2] + bv.z;
      o.w = acc3[ai][bj][3] + bv.w;
      *(float4*)(out + (size_t)(base + e) * 256 + col0) = o;
    }
  }
}

extern "C" void kernel_launch(void* const* d_in, const int* in_sizes, int n_in,
                              void* d_out, int out_size, void* d_ws, size_t ws_size,
                              hipStream_t stream) {
  const float* rel    = (const float*)d_in[0];
  const float* node   = (const float*)d_in[1];
  const int*   eidx   = (const int*)d_in[2];
  const float* quest  = (const float*)d_in[3];
  const int*   ebat   = (const int*)d_in[4];
  const float* Wrel   = (const float*)d_in[5];
  const float* Wnode  = (const float*)d_in[6];
  const float* Wq     = (const float*)d_in[7];
  const float* W1     = (const float*)d_in[8];
  const float* bias1  = (const float*)d_in[9];
  const float* W2     = (const float*)d_in[10];
  const float* bias2  = (const float*)d_in[11];
  float* outp = (float*)d_out;
  bf16* ws = (bf16*)d_ws;
  float* qgf = (float*)(ws + WS_QGF_B);
  bf16* akh = ws + WS_AKH;

  const int E = in_sizes[4];  // 400000

  prep_weights<<<640, 256, 0, stream>>>(Wrel, Wnode, W1, W2, ws);
  prep_qg<<<64, 256, 0, stream>>>(quest, Wq, qgf, ws + WS_QG);

  if (ws_size >= WS_SPLIT_BYTES) {
    k1_ak<<<E / 64, 256, 0, stream>>>(rel, node, eidx + E, ebat,
                                      ws + WS_PK1, ws + WS_QG, akh);
    k2_mlp1<<<E / 64, 256, 0, stream>>>(akh, ws + WS_PK2, bias1);
    k3_mlp2<<<E / 64, 256, 0, stream>>>(akh, ws + WS_PK3, bias2, outp);
  } else {
    fused_main<<<E / 64, 256, 0, stream>>>(
        rel, node, eidx + E, ebat,
        ws + WS_PK1, ws + WS_PK2, ws + WS_PK3, qgf,
        bias1, bias2, outp);
  }
}

// Round 21
// 561.531 us; speedup vs baseline: 1.0857x; 1.0857x over previous
//
#include <hip/hip_runtime.h>

typedef __bf16 bf16;
typedef bf16 bf16x4 __attribute__((ext_vector_type(4)));
typedef bf16 bf16x8 __attribute__((ext_vector_type(8)));
typedef float f32x4 __attribute__((ext_vector_type(4)));

// ws layout (bf16 element offsets):
//   PK1  32768 | PK2 65536 | PK3 65536 | QG bf16 16384 | QGF f32 (32768 slots)
//   AKH  bf16[E][256] = 204.8 MB
#define WS_PK1    0
#define WS_PK2    32768
#define WS_PK3    98304
#define WS_QG     163840
#define WS_QGF_B  180224
#define WS_AKH    212992
#define WS_SPLIT_BYTES (425984ull + 204800000ull)

__global__ void prep_weights(const float* __restrict__ Wrel,
                             const float* __restrict__ Wnode,
                             const float* __restrict__ W1,
                             const float* __restrict__ W2,
                             bf16* __restrict__ ws) {
  int id = blockIdx.x * 256 + threadIdx.x;
  if (id < 32768) {                       // PK1: cg(4) kk(4) ai(4) l(64) j(8)
    int cg = id >> 13, rem = id & 8191;
    int kk = rem >> 11;
    int ai = (rem >> 9) & 3;
    int l  = (rem >> 3) & 63;
    int j  = rem & 7;
    int n  = (cg & 1) * 64 + ai * 16 + (l & 15);
    int k  = kk * 32 + (l >> 4) * 8 + j;
    const float* src = (cg >> 1) ? Wnode : Wrel;
    ws[WS_PK1 + id] = (bf16)src[k * 128 + n];
  } else if (id < 98304) {                // PK2
    int t = id - 32768;
    int cg = t >> 14, rem = t & 16383;
    int kk = rem >> 11;
    int ai = (rem >> 9) & 3;
    int l  = (rem >> 3) & 63;
    int j  = rem & 7;
    int n  = cg * 64 + ai * 16 + (l & 15);
    int k  = kk * 32 + (l >> 4) * 8 + j;
    ws[WS_PK2 + t] = (bf16)W1[k * 256 + n];
  } else if (id < 163840) {               // PK3
    int t = id - 98304;
    int cg = t >> 14, rem = t & 16383;
    int kk = rem >> 11;
    int ai = (rem >> 9) & 3;
    int l  = (rem >> 3) & 63;
    int j  = rem & 7;
    int n  = cg * 64 + ai * 16 + (l & 15);
    int k  = kk * 32 + (l >> 4) * 8 + j;
    ws[WS_PK3 + t] = (bf16)W2[k * 256 + n];
  }
}

__global__ void prep_qg(const float* __restrict__ question,
                        const float* __restrict__ Wq,
                        float* __restrict__ qgf,
                        bf16* __restrict__ qg) {
  int b = blockIdx.x, c = threadIdx.x;
  float s = 0.f;
#pragma unroll 8
  for (int k = 0; k < 128; ++k) s += question[b * 128 + k] * Wq[k * 256 + c];
  float v = 1.f / (1.f + expf(-s));
  qgf[b * 256 + c] = v;
  qg[b * 256 + c]  = (bf16)v;
}

__device__ __forceinline__ float gelu_fast(float x) {
  float m = x * x;
  float t = fmaf(0.10294537f, m, 2.30220790f);
  float e = __builtin_amdgcn_exp2f(t * x);
  float r = __builtin_amdgcn_rcpf(e + 1.f);
  return x - x * r;
}

typedef __attribute__((address_space(1))) const void gq_t;
typedef __attribute__((address_space(3))) void lq_t;
#define GLD16(g, s) __builtin_amdgcn_global_load_lds((gq_t*)(g), (lq_t*)(s), 16, 0, 0)
#define SB() __builtin_amdgcn_sched_barrier(0xF)
#define WAIT_VM8()   { asm volatile("s_waitcnt vmcnt(8)" ::: "memory"); SB(); }
#define WAIT_VM4()   { asm volatile("s_waitcnt vmcnt(4)" ::: "memory"); SB(); }
#define WAIT_VM0()   { asm volatile("s_waitcnt vmcnt(0)" ::: "memory"); SB(); }
#define WAIT_LGKM0() { asm volatile("s_waitcnt lgkmcnt(0)" ::: "memory"); SB(); }
#define BAR() __builtin_amdgcn_s_barrier()

// ================= K1: AK = concat(rel@Wrel, node@Wnode)*gate =================
// Champion prefix: staging + G1 FIFO + gate, AK -> global. 64KB LDS, 2 blk/CU.
__global__ __launch_bounds__(256, 2) void k1_ak(
    const float* __restrict__ rel_tok,
    const float* __restrict__ node_tok,
    const int*   __restrict__ tail_idx,
    const int*   __restrict__ ebatch,
    const bf16*  __restrict__ pk1,
    const float* __restrict__ qgf,
    bf16* __restrict__ akh)
{
  __shared__ char s_buf[32768];   // tokens [2][64][128] bf16 swizzled
  __shared__ char s_w[32768];     // [slot 2][cg 4][4KB]

  const int tid = threadIdx.x;
  const int cg = tid >> 6, l = tid & 63, lo = l & 15, hi = l >> 4;
  const int base = blockIdx.x * 64;
  const int h1 = cg >> 1;

  auto issue_step = [&](int s) {
    const bf16* g = pk1 + cg * 8192 + s * 2048 + l * 8;
    char* d = s_w + (s & 1) * 16384 + cg * 4096;
#pragma unroll
    for (int ai = 0; ai < 4; ++ai) GLD16(g + ai * 512, d + ai * 1024);
  };

  int ebv[4];
#pragma unroll
  for (int bj = 0; bj < 4; ++bj) ebv[bj] = ebatch[base + bj * 16 + lo];
  float4 gv[4][4];
#pragma unroll
  for (int bj = 0; bj < 4; ++bj)
#pragma unroll
    for (int ai = 0; ai < 4; ++ai)
      gv[bj][ai] = *(const float4*)(qgf + ebv[bj] * 256 + cg * 64 + ai * 16 + hi * 4);

  {
    const float4* g = (const float4*)rel_tok + (size_t)base * 32;
#pragma unroll
    for (int i = 0; i < 8; ++i) {
      int idx = tid + i * 256;
      int row = idx >> 5, c4 = idx & 31;
      float4 v = g[idx];
      bf16x4 b; b[0] = (bf16)v.x; b[1] = (bf16)v.y; b[2] = (bf16)v.z; b[3] = (bf16)v.w;
      int off = row * 256 + ((c4 * 8) ^ ((row & 15) << 4));
      *(bf16x4*)(s_buf + off) = b;
    }
#pragma unroll
    for (int i = 0; i < 8; ++i) {
      int idx = tid + i * 256;
      int row = idx >> 5, c4 = idx & 31;
      int tail = tail_idx[base + row];
      float4 v = ((const float4*)node_tok)[(size_t)tail * 32 + c4];
      bf16x4 b; b[0] = (bf16)v.x; b[1] = (bf16)v.y; b[2] = (bf16)v.z; b[3] = (bf16)v.w;
      int off = 16384 + row * 256 + ((c4 * 8) ^ ((row & 15) << 4));
      *(bf16x4*)(s_buf + off) = b;
    }
  }

  WAIT_VM0();
  issue_step(0);
  issue_step(1);
  WAIT_LGKM0();
  BAR();

  const f32x4 zero4 = {0.f, 0.f, 0.f, 0.f};
  const int wb = cg * 4096 + l * 16;

  f32x4 acc[4][4];
#pragma unroll
  for (int ai = 0; ai < 4; ++ai)
#pragma unroll
    for (int bj = 0; bj < 4; ++bj) acc[ai][bj] = zero4;

#pragma unroll
  for (int kk = 0; kk < 4; ++kk) {
    if (kk < 3) { WAIT_VM4(); } else { WAIT_VM0(); }
    bf16x8 a[4];
#pragma unroll
    for (int ai = 0; ai < 4; ++ai)
      a[ai] = *(const bf16x8*)(s_w + (kk & 1) * 16384 + wb + ai * 1024);
    WAIT_LGKM0();
    if (kk + 2 < 4) issue_step(kk + 2);
    __builtin_amdgcn_s_setprio(1);
#pragma unroll
    for (int bj = 0; bj < 4; ++bj) {
      int e = bj * 16 + lo;
      bf16x8 b = *(const bf16x8*)(s_buf + h1 * 16384 + e * 256 +
                                  ((kk * 64 + hi * 16) ^ ((e & 15) << 4)));
#pragma unroll
      for (int ai = 0; ai < 4; ++ai)
        acc[ai][bj] = __builtin_amdgcn_mfma_f32_16x16x32_bf16(a[ai], b, acc[ai][bj], 0, 0, 0);
    }
    __builtin_amdgcn_s_setprio(0);
  }

#pragma unroll
  for (int bj = 0; bj < 4; ++bj) {
    int e = bj * 16 + lo;
#pragma unroll
    for (int ai = 0; ai < 4; ++ai) {
      int col0 = cg * 64 + ai * 16 + hi * 4;
      bf16x4 pk;
      pk[0] = (bf16)(acc[ai][bj][0] * gv[bj][ai].x);
      pk[1] = (bf16)(acc[ai][bj][1] * gv[bj][ai].y);
      pk[2] = (bf16)(acc[ai][bj][2] * gv[bj][ai].z);
      pk[3] = (bf16)(acc[ai][bj][3] * gv[bj][ai].w);
      *(bf16x4*)(akh + (size_t)(base + e) * 256 + col0) = pk;
    }
  }
}

// ================= K2/K3 shared body: Y = act(X @ W + b) =================
// Weight FIFO (2-slot LDS, counted vmcnt) + triple-buffered b-frag register
// prefetch (lead 2). 32KB LDS, no barriers in the stream (K2: one, in-place).
// Ledger: prologue {w0,b0,b1,w1}=16 in flight; iter kk waits vmcnt(8)
// (w_kk,b_kk done), issues b_{kk+2}, w_{kk+2}; last iter vmcnt(0).
template <bool GELU>
__device__ __forceinline__ void mlp_body(
    const bf16* __restrict__ x,      // [E][256] bf16 activations
    const bf16* __restrict__ pk,     // packed weights
    const float* __restrict__ bias,
    char* s_w, int base, f32x4 (&acc)[4][4])
{
  const int tid = threadIdx.x;
  const int cg = tid >> 6, l = tid & 63, lo = l & 15, hi = l >> 4;

  auto issue_w = [&](int s) {
    const bf16* g = pk + cg * 16384 + s * 2048 + l * 8;
    char* d = s_w + (s & 1) * 16384 + cg * 4096;
#pragma unroll
    for (int ai = 0; ai < 4; ++ai) GLD16(g + ai * 512, d + ai * 1024);
  };

  const f32x4 zero4 = {0.f, 0.f, 0.f, 0.f};
#pragma unroll
  for (int ai = 0; ai < 4; ++ai)
#pragma unroll
    for (int bj = 0; bj < 4; ++bj) acc[ai][bj] = zero4;

  bf16x8 bb[3][4];                 // triple-buffered b-frags (kk%3)
  const int wb = cg * 4096 + l * 16;

  // prologue: w0, b0, b1, w1  (16 outstanding)
  WAIT_VM0();
  issue_w(0);
#pragma unroll
  for (int bj = 0; bj < 4; ++bj) {
    int e = bj * 16 + lo;
    bb[0][bj] = *(const bf16x8*)(x + (size_t)(base + e) * 256 + 0 * 32 + hi * 8);
  }
#pragma unroll
  for (int bj = 0; bj < 4; ++bj) {
    int e = bj * 16 + lo;
    bb[1][bj] = *(const bf16x8*)(x + (size_t)(base + e) * 256 + 1 * 32 + hi * 8);
  }
  issue_w(1);

#pragma unroll
  for (int kk = 0; kk < 8; ++kk) {
    if (kk < 7) { WAIT_VM8(); } else { WAIT_VM0(); }
    bf16x8 a[4];
#pragma unroll
    for (int ai = 0; ai < 4; ++ai)
      a[ai] = *(const bf16x8*)(s_w + (kk & 1) * 16384 + wb + ai * 1024);
    WAIT_LGKM0();
    if (kk + 2 < 8) {
#pragma unroll
      for (int bj = 0; bj < 4; ++bj) {
        int e = bj * 16 + lo;
        bb[(kk + 2) % 3][bj] =
            *(const bf16x8*)(x + (size_t)(base + e) * 256 + (kk + 2) * 32 + hi * 8);
      }
      issue_w(kk + 2);
    }
    __builtin_amdgcn_s_setprio(1);
#pragma unroll
    for (int ai = 0; ai < 4; ++ai)
#pragma unroll
      for (int bj = 0; bj < 4; ++bj)
        acc[ai][bj] = __builtin_amdgcn_mfma_f32_16x16x32_bf16(a[ai], bb[kk % 3][bj], acc[ai][bj], 0, 0, 0);
    __builtin_amdgcn_s_setprio(0);
  }
}

__global__ __launch_bounds__(256, 3) void k2_mlp1(
    bf16* __restrict__ akh,
    const bf16* __restrict__ pk2,
    const float* __restrict__ b1)
{
  __shared__ char s_w[32768];
  const int tid = threadIdx.x;
  const int cg = tid >> 6, l = tid & 63, lo = l & 15, hi = l >> 4;
  const int base = blockIdx.x * 64;

  float4 bv[4];
#pragma unroll
  for (int ai = 0; ai < 4; ++ai)
    bv[ai] = *(const float4*)(b1 + cg * 64 + ai * 16 + hi * 4);

  f32x4 acc[4][4];
  mlp_body<true>(akh, pk2, b1, s_w, base, acc);

  // in-place: all reads (vmcnt drained by body tail) + cross-wave barrier
  BAR();

#pragma unroll
  for (int bj = 0; bj < 4; ++bj) {
    int e = bj * 16 + lo;
#pragma unroll
    for (int ai = 0; ai < 4; ++ai) {
      int col0 = cg * 64 + ai * 16 + hi * 4;
      bf16x4 pk;
      pk[0] = (bf16)gelu_fast(acc[ai][bj][0] + bv[ai].x);
      pk[1] = (bf16)gelu_fast(acc[ai][bj][1] + bv[ai].y);
      pk[2] = (bf16)gelu_fast(acc[ai][bj][2] + bv[ai].z);
      pk[3] = (bf16)gelu_fast(acc[ai][bj][3] + bv[ai].w);
      *(bf16x4*)(akh + (size_t)(base + e) * 256 + col0) = pk;
    }
  }
}

__global__ __launch_bounds__(256, 3) void k3_mlp2(
    const bf16* __restrict__ akh,
    const bf16* __restrict__ pk3,
    const float* __restrict__ b2,
    float* __restrict__ out)
{
  __shared__ char s_w[32768];
  const int tid = threadIdx.x;
  const int cg = tid >> 6, l = tid & 63, lo = l & 15, hi = l >> 4;
  const int base = blockIdx.x * 64;

  float4 bv[4];
#pragma unroll
  for (int ai = 0; ai < 4; ++ai)
    bv[ai] = *(const float4*)(b2 + cg * 64 + ai * 16 + hi * 4);

  f32x4 acc[4][4];
  mlp_body<false>(akh, pk3, b2, s_w, base, acc);

#pragma unroll
  for (int bj = 0; bj < 4; ++bj) {
    int e = bj * 16 + lo;
#pragma unroll
    for (int ai = 0; ai < 4; ++ai) {
      int col0 = cg * 64 + ai * 16 + hi * 4;
      float4 o;
      o.x = acc[ai][bj][0] + bv[ai].x;
      o.y = acc[ai][bj][1] + bv[ai].y;
      o.z = acc[ai][bj][2] + bv[ai].z;
      o.w = acc[ai][bj][3] + bv[ai].w;
      *(float4*)(out + (size_t)(base + e) * 256 + col0) = o;
    }
  }
}

// ================= FUSED FALLBACK (R19 champion) =================
__global__ __launch_bounds__(256, 2) void fused_main(
    const float* __restrict__ rel_tok,
    const float* __restrict__ node_tok,
    const int*   __restrict__ tail_idx,
    const int*   __restrict__ ebatch,
    const bf16*  __restrict__ pk1,
    const bf16*  __restrict__ pk2,
    const bf16*  __restrict__ pk3,
    const float* __restrict__ qgf,
    const float* __restrict__ b1,
    const float* __restrict__ b2,
    float* __restrict__ out)
{
  __shared__ char  s_buf[32768];
  __shared__ char  s_w[32768];
  __shared__ float s_bias[512];

  const int tid = threadIdx.x;
  const int cg  = tid >> 6;
  const int l   = tid & 63;
  const int lo  = l & 15;
  const int hi  = l >> 4;
  const int base = blockIdx.x * 64;
  const int h1  = cg >> 1;

  auto issue_step = [&](int s) {
    const bf16* g;
    if (s < 4)       g = pk1 + cg * 8192  + s * 2048;
    else if (s < 12) g = pk2 + cg * 16384 + (s - 4) * 2048;
    else             g = pk3 + cg * 16384 + (s - 12) * 2048;
    g += l * 8;
    char* d = s_w + (s & 1) * 16384 + cg * 4096;
#pragma unroll
    for (int ai = 0; ai < 4; ++ai) GLD16(g + ai * 512, d + ai * 1024);
  };

  int ebv[4];
#pragma unroll
  for (int bj = 0; bj < 4; ++bj) ebv[bj] = ebatch[base + bj * 16 + lo];
  float4 gv[4][4];
#pragma unroll
  for (int bj = 0; bj < 4; ++bj)
#pragma unroll
    for (int ai = 0; ai < 4; ++ai)
      gv[bj][ai] = *(const float4*)(qgf + ebv[bj] * 256 + cg * 64 + ai * 16 + hi * 4);
  s_bias[tid]       = b1[tid];
  s_bias[256 + tid] = b2[tid];

  {
    const float4* g = (const float4*)rel_tok + (size_t)base * 32;
#pragma unroll
    for (int i = 0; i < 8; ++i) {
      int idx = tid + i * 256;
      int row = idx >> 5, c4 = idx & 31;
      float4 v = g[idx];
      bf16x4 b; b[0] = (bf16)v.x; b[1] = (bf16)v.y; b[2] = (bf16)v.z; b[3] = (bf16)v.w;
      int off = row * 256 + ((c4 * 8) ^ ((row & 15) << 4));
      *(bf16x4*)(s_buf + off) = b;
    }
#pragma unroll
    for (int i = 0; i < 8; ++i) {
      int idx = tid + i * 256;
      int row = idx >> 5, c4 = idx & 31;
      int tail = tail_idx[base + row];
      float4 v = ((const float4*)node_tok)[(size_t)tail * 32 + c4];
      bf16x4 b; b[0] = (bf16)v.x; b[1] = (bf16)v.y; b[2] = (bf16)v.z; b[3] = (bf16)v.w;
      int off = 16384 + row * 256 + ((c4 * 8) ^ ((row & 15) << 4));
      *(bf16x4*)(s_buf + off) = b;
    }
  }

  WAIT_VM0();
  issue_step(0);
  issue_step(1);
  WAIT_LGKM0();
  BAR();

  const f32x4 zero4 = {0.f, 0.f, 0.f, 0.f};
  const int wb = cg * 4096 + l * 16;

  f32x4 acc1[4][4];
#pragma unroll
  for (int ai = 0; ai < 4; ++ai)
#pragma unroll
    for (int bj = 0; bj < 4; ++bj) acc1[ai][bj] = zero4;

#pragma unroll
  for (int kk = 0; kk < 4; ++kk) {
    WAIT_VM4();
    bf16x8 a[4];
#pragma unroll
    for (int ai = 0; ai < 4; ++ai)
      a[ai] = *(const bf16x8*)(s_w + (kk & 1) * 16384 + wb + ai * 1024);
    WAIT_LGKM0();
    issue_step(kk + 2);
    __builtin_amdgcn_s_setprio(1);
#pragma unroll
    for (int bj = 0; bj < 4; ++bj) {
      int e = bj * 16 + lo;
      bf16x8 b = *(const bf16x8*)(s_buf + h1 * 16384 + e * 256 +
                                  ((kk * 64 + hi * 16) ^ ((e & 15) << 4)));
#pragma unroll
      for (int ai = 0; ai < 4; ++ai)
        acc1[ai][bj] = __builtin_amdgcn_mfma_f32_16x16x32_bf16(a[ai], b, acc1[ai][bj], 0, 0, 0);
    }
    __builtin_amdgcn_s_setprio(0);
  }
  BAR();

#pragma unroll
  for (int bj = 0; bj < 4; ++bj) {
    int e = bj * 16 + lo;
#pragma unroll
    for (int ai = 0; ai < 4; ++ai) {
      int col0 = cg * 64 + ai * 16 + hi * 4;
      bf16x4 pk;
      pk[0] = (bf16)(acc1[ai][bj][0] * gv[bj][ai].x);
      pk[1] = (bf16)(acc1[ai][bj][1] * gv[bj][ai].y);
      pk[2] = (bf16)(acc1[ai][bj][2] * gv[bj][ai].z);
      pk[3] = (bf16)(acc1[ai][bj][3] * gv[bj][ai].w);
      int off = e * 512 + ((2 * col0) ^ ((e & 15) << 4));
      *(bf16x4*)(s_buf + off) = pk;
    }
  }
  WAIT_LGKM0();
  BAR();

  f32x4 acc2[4][4];
#pragma unroll
  for (int ai = 0; ai < 4; ++ai)
#pragma unroll
    for (int bj = 0; bj < 4; ++bj) acc2[ai][bj] = zero4;

#pragma unroll
  for (int kk = 0; kk < 8; ++kk) {
    const int s = 4 + kk;
    WAIT_VM4();
    bf16x8 a[4];
#pragma unroll
    for (int ai = 0; ai < 4; ++ai)
      a[ai] = *(const bf16x8*)(s_w + (s & 1) * 16384 + wb + ai * 1024);
    WAIT_LGKM0();
    issue_step(s + 2);
    __builtin_amdgcn_s_setprio(1);
#pragma unroll
    for (int bj = 0; bj < 4; ++bj) {
      int e = bj * 16 + lo;
      bf16x8 b = *(const bf16x8*)(s_buf + e * 512 +
                                  ((kk * 64 + hi * 16) ^ ((e & 15) << 4)));
#pragma unroll
      for (int ai = 0; ai < 4; ++ai)
        acc2[ai][bj] = __builtin_amdgcn_mfma_f32_16x16x32_bf16(a[ai], b, acc2[ai][bj], 0, 0, 0);
    }
    __builtin_amdgcn_s_setprio(0);
  }
  BAR();

#pragma unroll
  for (int bj = 0; bj < 4; ++bj) {
    int e = bj * 16 + lo;
#pragma unroll
    for (int ai = 0; ai < 4; ++ai) {
      int col0 = cg * 64 + ai * 16 + hi * 4;
      float4 bvv = *(const float4*)(s_bias + col0);
      bf16x4 pk;
      pk[0] = (bf16)gelu_fast(acc2[ai][bj][0] + bvv.x);
      pk[1] = (bf16)gelu_fast(acc2[ai][bj][1] + bvv.y);
      pk[2] = (bf16)gelu_fast(acc2[ai][bj][2] + bvv.z);
      pk[3] = (bf16)gelu_fast(acc2[ai][bj][3] + bvv.w);
      int off = e * 512 + ((2 * col0) ^ ((e & 15) << 4));
      *(bf16x4*)(s_buf + off) = pk;
    }
  }
  WAIT_LGKM0();
  BAR();

  f32x4 acc3[4][4];
#pragma unroll
  for (int ai = 0; ai < 4; ++ai)
#pragma unroll
    for (int bj = 0; bj < 4; ++bj) acc3[ai][bj] = zero4;

#pragma unroll
  for (int kk = 0; kk < 8; ++kk) {
    const int s = 12 + kk;
    if (s < 19) { WAIT_VM4(); } else { WAIT_VM0(); }
    bf16x8 a[4];
#pragma unroll
    for (int ai = 0; ai < 4; ++ai)
      a[ai] = *(const bf16x8*)(s_w + (s & 1) * 16384 + wb + ai * 1024);
    WAIT_LGKM0();
    if (s + 2 <= 19) issue_step(s + 2);
    __builtin_amdgcn_s_setprio(1);
#pragma unroll
    for (int bj = 0; bj < 4; ++bj) {
      int e = bj * 16 + lo;
      bf16x8 b = *(const bf16x8*)(s_buf + e * 512 +
                                  ((kk * 64 + hi * 16) ^ ((e & 15) << 4)));
#pragma unroll
      for (int ai = 0; ai < 4; ++ai)
        acc3[ai][bj] = __builtin_amdgcn_mfma_f32_16x16x32_bf16(a[ai], b, acc3[ai][bj], 0, 0, 0);
    }
    __builtin_amdgcn_s_setprio(0);
  }

#pragma unroll
  for (int bj = 0; bj < 4; ++bj) {
    int e = bj * 16 + lo;
#pragma unroll
    for (int ai = 0; ai < 4; ++ai) {
      int col0 = cg * 64 + ai * 16 + hi * 4;
      float4 bvv = *(const float4*)(s_bias + 256 + col0);
      float4 o;
      o.x = acc3[ai][bj][0] + bvv.x;
      o.y = acc3[ai][bj][1] + bvv.y;
      o.z = acc3[ai][bj][2] + bvv.z;
      o.w = acc3[ai][bj][3] + bvv.w;
      *(float4*)(out + (size_t)(base + e) * 256 + col0) = o;
    }
  }
}

extern "C" void kernel_launch(void* const* d_in, const int* in_sizes, int n_in,
                              void* d_out, int out_size, void* d_ws, size_t ws_size,
                              hipStream_t stream) {
  const float* rel    = (const float*)d_in[0];
  const float* node   = (const float*)d_in[1];
  const int*   eidx   = (const int*)d_in[2];
  const float* quest  = (const float*)d_in[3];
  const int*   ebat   = (const int*)d_in[4];
  const float* Wrel   = (const float*)d_in[5];
  const float* Wnode  = (const float*)d_in[6];
  const float* Wq     = (const float*)d_in[7];
  const float* W1     = (const float*)d_in[8];
  const float* bias1  = (const float*)d_in[9];
  const float* W2     = (const float*)d_in[10];
  const float* bias2  = (const float*)d_in[11];
  float* outp = (float*)d_out;
  bf16* ws = (bf16*)d_ws;
  float* qgf = (float*)(ws + WS_QGF_B);
  bf16* akh = ws + WS_AKH;

  const int E = in_sizes[4];  // 400000

  prep_weights<<<640, 256, 0, stream>>>(Wrel, Wnode, W1, W2, ws);
  prep_qg<<<64, 256, 0, stream>>>(quest, Wq, qgf, ws + WS_QG);

  if (ws_size >= WS_SPLIT_BYTES) {
    k1_ak<<<E / 64, 256, 0, stream>>>(rel, node, eidx + E, ebat,
                                      ws + WS_PK1, qgf, akh);
    k2_mlp1<<<E / 64, 256, 0, stream>>>(akh, ws + WS_PK2, bias1);
    k3_mlp2<<<E / 64, 256, 0, stream>>>(akh, ws + WS_PK3, bias2, outp);
  } else {
    fused_main<<<E / 64, 256, 0, stream>>>(
        rel, node, eidx + E, ebat,
        ws + WS_PK1, ws + WS_PK2, ws + WS_PK3, qgf,
        bias1, bias2, outp);
  }
}

// Round 23
// 272.664 us; speedup vs baseline: 2.2359x; 2.0594x over previous
//
#include <hip/hip_runtime.h>

typedef __bf16 bf16;
typedef bf16 bf16x4 __attribute__((ext_vector_type(4)));
typedef bf16 bf16x8 __attribute__((ext_vector_type(8)));
typedef float f32x4 __attribute__((ext_vector_type(4)));

// ws layout (bf16 element offsets):
//   PK1  [4][4][4][64][8] = 32768    GEMM1 weights, fragment-packed
//   PK2  [4][8][4][64][8] = 65536    W1
//   PK3  [4][8][4][64][8] = 65536    W2
//   QGF  float[64][256]   at bf16-offset 163840
#define WS_PK1    0
#define WS_PK2    32768
#define WS_PK3    98304
#define WS_QGF_B  163840

// ---------- prep: pack weights into per-(cg,kk,ai) contiguous 1KB fragments ----------
__global__ void prep_weights(const float* __restrict__ Wrel,
                             const float* __restrict__ Wnode,
                             const float* __restrict__ W1,
                             const float* __restrict__ W2,
                             bf16* __restrict__ ws) {
  int id = blockIdx.x * 256 + threadIdx.x;
  if (id < 32768) {                       // PK1: cg(4) kk(4) ai(4) l(64) j(8)
    int cg = id >> 13, rem = id & 8191;
    int kk = rem >> 11;
    int ai = (rem >> 9) & 3;
    int l  = (rem >> 3) & 63;
    int j  = rem & 7;
    int n  = (cg & 1) * 64 + ai * 16 + (l & 15);
    int k  = kk * 32 + (l >> 4) * 8 + j;
    const float* src = (cg >> 1) ? Wnode : Wrel;
    ws[WS_PK1 + id] = (bf16)src[k * 128 + n];
  } else if (id < 98304) {                // PK2: cg(4) kk(8) ai(4) l(64) j(8)
    int t = id - 32768;
    int cg = t >> 14, rem = t & 16383;
    int kk = rem >> 11;
    int ai = (rem >> 9) & 3;
    int l  = (rem >> 3) & 63;
    int j  = rem & 7;
    int n  = cg * 64 + ai * 16 + (l & 15);
    int k  = kk * 32 + (l >> 4) * 8 + j;
    ws[WS_PK2 + t] = (bf16)W1[k * 256 + n];
  } else if (id < 163840) {               // PK3
    int t = id - 98304;
    int cg = t >> 14, rem = t & 16383;
    int kk = rem >> 11;
    int ai = (rem >> 9) & 3;
    int l  = (rem >> 3) & 63;
    int j  = rem & 7;
    int n  = cg * 64 + ai * 16 + (l & 15);
    int k  = kk * 32 + (l >> 4) * 8 + j;
    ws[WS_PK3 + t] = (bf16)W2[k * 256 + n];
  }
}

// ---------- prep: qg[64][256] = sigmoid(question @ W_qgate), fp32 ----------
__global__ void prep_qg(const float* __restrict__ question,
                        const float* __restrict__ Wq,
                        float* __restrict__ qgf) {
  int b = blockIdx.x, c = threadIdx.x;
  float s = 0.f;
#pragma unroll 8
  for (int k = 0; k < 128; ++k) s += question[b * 128 + k] * Wq[k * 256 + c];
  qgf[b * 256 + c] = 1.f / (1.f + expf(-s));
}

// tanh-form GELU, exp2-direct. max |diff vs erf-GELU| ~5e-4 << 1.23e-2 budget.
__device__ __forceinline__ float gelu_fast(float x) {
  float m = x * x;
  float t = fmaf(0.10294537f, m, 2.30220790f);
  float e = __builtin_amdgcn_exp2f(t * x);
  float r = __builtin_amdgcn_rcpf(e + 1.f);
  return x - x * r;
}

typedef __attribute__((address_space(1))) const void gq_t;
typedef __attribute__((address_space(3))) void lq_t;
#define GLD16(g, s) __builtin_amdgcn_global_load_lds((gq_t*)(g), (lq_t*)(s), 16, 0, 0)
// sched_barrier mask 0xF = ALU|VALU|SALU|MFMA may cross; DS/VMEM pinned.
#define SB() __builtin_amdgcn_sched_barrier(0xF)
#define WAIT_VM4()   { asm volatile("s_waitcnt vmcnt(4)" ::: "memory"); SB(); }
#define WAIT_VM0()   { asm volatile("s_waitcnt vmcnt(0)" ::: "memory"); SB(); }
#define WAIT_LGKM0() { asm volatile("s_waitcnt lgkmcnt(0)" ::: "memory"); SB(); }
#define BAR() __builtin_amdgcn_s_barrier()

// ---------- main: 64 edges/block, 4 waves (1 cg each), 2 blocks/CU ----------
// R12/R19 champion: wave-private 2-slot weight FIFO in LDS fed by
// global_load_lds, depth-2 counted vmcnt (never drained mid-loop);
// swapped-operand MFMA (D = W x X^T); exp2 GELU; fp32 gate table.
// R22b: nontemporal rel-token loads + output stores via ext_vector f32x4
// (zero-reuse streams stop evicting node-gather / weights from L2/L3).
__global__ __launch_bounds__(256, 2) void fused_main(
    const float* __restrict__ rel_tok,   // [E,128]
    const float* __restrict__ node_tok,  // [N,128]
    const int*   __restrict__ tail_idx,  // edge_index + E
    const int*   __restrict__ ebatch,    // [E]
    const bf16*  __restrict__ pk1,
    const bf16*  __restrict__ pk2,
    const bf16*  __restrict__ pk3,
    const float* __restrict__ qgf,       // [64][256] fp32
    const float* __restrict__ b1,
    const float* __restrict__ b2,
    float* __restrict__ out)             // [E,256]
{
  // s_buf 32KB union: tokens [2][64][128] bf16 (h*16384 + e*256 + swz)
  //                   AK/H   [64][256]    bf16 (e*512 + swz)
  // s_w   32KB: [slot 2][cg 4][4KB]
  __shared__ char  s_buf[32768];
  __shared__ char  s_w[32768];
  __shared__ float s_bias[512];          // b1 | b2

  const int tid = threadIdx.x;
  const int cg  = tid >> 6;       // wave = col group, cols [cg*64, cg*64+64)
  const int l   = tid & 63;
  const int lo  = l & 15;
  const int hi  = l >> 4;
  const int base = blockIdx.x * 64;
  const int h1  = cg >> 1;        // GEMM1 half (0=rel, 1=node)

  auto issue_step = [&](int s) {   // s compile-time after unroll
    const bf16* g;
    if (s < 4)       g = pk1 + cg * 8192  + s * 2048;
    else if (s < 12) g = pk2 + cg * 16384 + (s - 4) * 2048;
    else             g = pk3 + cg * 16384 + (s - 12) * 2048;
    g += l * 8;
    char* d = s_w + (s & 1) * 16384 + cg * 4096;
#pragma unroll
    for (int ai = 0; ai < 4; ++ai) GLD16(g + ai * 512, d + ai * 1024);
  };

  // ---- pre-FIFO VMEM: fp32 gate fragments (64 VGPR, dead by B_c), biases -> LDS ----
  int ebv[4];
#pragma unroll
  for (int bj = 0; bj < 4; ++bj) ebv[bj] = ebatch[base + bj * 16 + lo];
  f32x4 gv[4][4];
#pragma unroll
  for (int bj = 0; bj < 4; ++bj)
#pragma unroll
    for (int ai = 0; ai < 4; ++ai)
      gv[bj][ai] = *(const f32x4*)(qgf + ebv[bj] * 256 + cg * 64 + ai * 16 + hi * 4);
  s_bias[tid]       = b1[tid];
  s_bias[256 + tid] = b2[tid];

  // ---- stage tokens -> LDS bf16 ((row&15) XOR swizzle) ----
  {
    const f32x4* g = (const f32x4*)rel_tok + (size_t)base * 32;
#pragma unroll
    for (int i = 0; i < 8; ++i) {
      int idx = tid + i * 256;          // over [64][32] float4
      int row = idx >> 5, c4 = idx & 31;
      f32x4 v = __builtin_nontemporal_load(g + idx);   // read-once stream
      bf16x4 b; b[0] = (bf16)v[0]; b[1] = (bf16)v[1]; b[2] = (bf16)v[2]; b[3] = (bf16)v[3];
      int off = row * 256 + ((c4 * 8) ^ ((row & 15) << 4));
      *(bf16x4*)(s_buf + off) = b;
    }
#pragma unroll
    for (int i = 0; i < 8; ++i) {
      int idx = tid + i * 256;
      int row = idx >> 5, c4 = idx & 31;
      int tail = tail_idx[base + row];  // 32 lanes same addr
      f32x4 v = ((const f32x4*)node_tok)[(size_t)tail * 32 + c4];  // reused: cache normally
      bf16x4 b; b[0] = (bf16)v[0]; b[1] = (bf16)v[1]; b[2] = (bf16)v[2]; b[3] = (bf16)v[3];
      int off = 16384 + row * 256 + ((c4 * 8) ^ ((row & 15) << 4));
      *(bf16x4*)(s_buf + off) = b;
    }
  }

  WAIT_VM0();                           // clean vmcnt slate before FIFO starts
  issue_step(0);
  issue_step(1);
  WAIT_LGKM0();                         // token/bias LDS writes done
  BAR();                                // B_a: tokens + biases visible

  const f32x4 zero4 = {0.f, 0.f, 0.f, 0.f};
  const int wb = cg * 4096 + l * 16;    // lane's read offset within a slot half

  // ================= GEMM1: steps 0..3, b from token region =================
  f32x4 acc1[4][4];
#pragma unroll
  for (int ai = 0; ai < 4; ++ai)
#pragma unroll
    for (int bj = 0; bj < 4; ++bj) acc1[ai][bj] = zero4;

#pragma unroll
  for (int kk = 0; kk < 4; ++kk) {
    const int s = kk;
    WAIT_VM4();                         // step s resident (s+1 in flight)
    bf16x8 a[4];
#pragma unroll
    for (int ai = 0; ai < 4; ++ai)
      a[ai] = *(const bf16x8*)(s_w + (s & 1) * 16384 + wb + ai * 1024);
    WAIT_LGKM0();                       // a[] in regs before slot reuse
    issue_step(s + 2);
    __builtin_amdgcn_s_setprio(1);
#pragma unroll
    for (int bj = 0; bj < 4; ++bj) {
      int e = bj * 16 + lo;
      bf16x8 b = *(const bf16x8*)(s_buf + h1 * 16384 + e * 256 +
                                  ((kk * 64 + hi * 16) ^ ((e & 15) << 4)));
#pragma unroll
      for (int ai = 0; ai < 4; ++ai)
        acc1[ai][bj] = __builtin_amdgcn_mfma_f32_16x16x32_bf16(a[ai], b, acc1[ai][bj], 0, 0, 0);
    }
    __builtin_amdgcn_s_setprio(0);
  }
  BAR();                                // B_b: all token reads done

  // gate + pack -> AK over token buffer (fp32 gate: no cvt)
#pragma unroll
  for (int bj = 0; bj < 4; ++bj) {
    int e = bj * 16 + lo;
#pragma unroll
    for (int ai = 0; ai < 4; ++ai) {
      int col0 = cg * 64 + ai * 16 + hi * 4;
      bf16x4 pk;
      pk[0] = (bf16)(acc1[ai][bj][0] * gv[bj][ai][0]);
      pk[1] = (bf16)(acc1[ai][bj][1] * gv[bj][ai][1]);
      pk[2] = (bf16)(acc1[ai][bj][2] * gv[bj][ai][2]);
      pk[3] = (bf16)(acc1[ai][bj][3] * gv[bj][ai][3]);
      int off = e * 512 + ((2 * col0) ^ ((e & 15) << 4));
      *(bf16x4*)(s_buf + off) = pk;
    }
  }
  WAIT_LGKM0();
  BAR();                                // B_c: AK visible

  // ================= GEMM2: steps 4..11, b from AK =================
  f32x4 acc2[4][4];
#pragma unroll
  for (int ai = 0; ai < 4; ++ai)
#pragma unroll
    for (int bj = 0; bj < 4; ++bj) acc2[ai][bj] = zero4;

#pragma unroll
  for (int kk = 0; kk < 8; ++kk) {
    const int s = 4 + kk;
    WAIT_VM4();
    bf16x8 a[4];
#pragma unroll
    for (int ai = 0; ai < 4; ++ai)
      a[ai] = *(const bf16x8*)(s_w + (s & 1) * 16384 + wb + ai * 1024);
    WAIT_LGKM0();
    issue_step(s + 2);
    __builtin_amdgcn_s_setprio(1);
#pragma unroll
    for (int bj = 0; bj < 4; ++bj) {
      int e = bj * 16 + lo;
      bf16x8 b = *(const bf16x8*)(s_buf + e * 512 +
                                  ((kk * 64 + hi * 16) ^ ((e & 15) << 4)));
#pragma unroll
      for (int ai = 0; ai < 4; ++ai)
        acc2[ai][bj] = __builtin_amdgcn_mfma_f32_16x16x32_bf16(a[ai], b, acc2[ai][bj], 0, 0, 0);
    }
    __builtin_amdgcn_s_setprio(0);
  }
  BAR();                                // B_d: all AK reads done

  // gelu + bias -> H (bias from LDS: no VMEM in FIFO window)
#pragma unroll
  for (int bj = 0; bj < 4; ++bj) {
    int e = bj * 16 + lo;
#pragma unroll
    for (int ai = 0; ai < 4; ++ai) {
      int col0 = cg * 64 + ai * 16 + hi * 4;
      f32x4 bv = *(const f32x4*)(s_bias + col0);
      bf16x4 pk;
      pk[0] = (bf16)gelu_fast(acc2[ai][bj][0] + bv[0]);
      pk[1] = (bf16)gelu_fast(acc2[ai][bj][1] + bv[1]);
      pk[2] = (bf16)gelu_fast(acc2[ai][bj][2] + bv[2]);
      pk[3] = (bf16)gelu_fast(acc2[ai][bj][3] + bv[3]);
      int off = e * 512 + ((2 * col0) ^ ((e & 15) << 4));
      *(bf16x4*)(s_buf + off) = pk;
    }
  }
  WAIT_LGKM0();
  BAR();                                // B_e: H visible

  // ================= GEMM3: steps 12..19, b from H =================
  f32x4 acc3[4][4];
#pragma unroll
  for (int ai = 0; ai < 4; ++ai)
#pragma unroll
    for (int bj = 0; bj < 4; ++bj) acc3[ai][bj] = zero4;

#pragma unroll
  for (int kk = 0; kk < 8; ++kk) {
    const int s = 12 + kk;
    if (s < 19) { WAIT_VM4(); } else { WAIT_VM0(); }
    bf16x8 a[4];
#pragma unroll
    for (int ai = 0; ai < 4; ++ai)
      a[ai] = *(const bf16x8*)(s_w + (s & 1) * 16384 + wb + ai * 1024);
    WAIT_LGKM0();
    if (s + 2 <= 19) issue_step(s + 2);
    __builtin_amdgcn_s_setprio(1);
#pragma unroll
    for (int bj = 0; bj < 4; ++bj) {
      int e = bj * 16 + lo;
      bf16x8 b = *(const bf16x8*)(s_buf + e * 512 +
                                  ((kk * 64 + hi * 16) ^ ((e & 15) << 4)));
#pragma unroll
      for (int ai = 0; ai < 4; ++ai)
        acc3[ai][bj] = __builtin_amdgcn_mfma_f32_16x16x32_bf16(a[ai], b, acc3[ai][bj], 0, 0, 0);
    }
    __builtin_amdgcn_s_setprio(0);
  }

  // bias + store (nontemporal f32x4: out is never re-read)
#pragma unroll
  for (int bj = 0; bj < 4; ++bj) {
    int e = bj * 16 + lo;
#pragma unroll
    for (int ai = 0; ai < 4; ++ai) {
      int col0 = cg * 64 + ai * 16 + hi * 4;
      f32x4 bv = *(const f32x4*)(s_bias + 256 + col0);
      f32x4 o;
      o[0] = acc3[ai][bj][0] + bv[0];
      o[1] = acc3[ai][bj][1] + bv[1];
      o[2] = acc3[ai][bj][2] + bv[2];
      o[3] = acc3[ai][bj][3] + bv[3];
      __builtin_nontemporal_store(o, (f32x4*)(out + (size_t)(base + e) * 256 + col0));
    }
  }
}

extern "C" void kernel_launch(void* const* d_in, const int* in_sizes, int n_in,
                              void* d_out, int out_size, void* d_ws, size_t ws_size,
                              hipStream_t stream) {
  const float* rel    = (const float*)d_in[0];
  const float* node   = (const float*)d_in[1];
  const int*   eidx   = (const int*)d_in[2];
  const float* quest  = (const float*)d_in[3];
  const int*   ebat   = (const int*)d_in[4];
  const float* Wrel   = (const float*)d_in[5];
  const float* Wnode  = (const float*)d_in[6];
  const float* Wq     = (const float*)d_in[7];
  const float* W1     = (const float*)d_in[8];
  const float* bias1  = (const float*)d_in[9];
  const float* W2     = (const float*)d_in[10];
  const float* bias2  = (const float*)d_in[11];
  float* outp = (float*)d_out;
  bf16* ws = (bf16*)d_ws;
  float* qgf = (float*)(ws + WS_QGF_B);

  const int E = in_sizes[4];  // 400000

  prep_weights<<<640, 256, 0, stream>>>(Wrel, Wnode, W1, W2, ws);
  prep_qg<<<64, 256, 0, stream>>>(quest, Wq, qgf);
  fused_main<<<E / 64, 256, 0, stream>>>(
      rel, node, eidx + E, ebat,
      ws + WS_PK1, ws + WS_PK2, ws + WS_PK3, qgf,
      bias1, bias2, outp);
}